// Round 8
// baseline (252.939 us; speedup 1.0000x reference)
//
#include <hip/hip_runtime.h>
#include <hip/hip_bf16.h>
#include <math.h>

// Problem constants: B=8, N=2048, F=128, W=64
constexpr int B = 8;
constexpr int N = 2048;
constexpr int F = 128;
constexpr int W = 64;

constexpr int TQ = 128;    // query rows per attention block (8 waves)
constexpr int TK = 64;     // key rows per K-tile iteration
constexpr int KSPLIT = 4;  // flash-decoding split over keys
constexpr int TILES_PER_SPLIT = (N / TK) / KSPLIT;   // 8

typedef short bf16x8 __attribute__((ext_vector_type(8)));   // 8 bf16 in 4 VGPRs
typedef float f32x4  __attribute__((ext_vector_type(4)));   // MFMA accumulator

__device__ inline ushort f2bf(float f) {
  union { float f; uint u; } v; v.f = f;
  uint u = v.u;
  return (ushort)((u + 0x7FFFu + ((u >> 16) & 1u)) >> 16);  // RNE
}
__device__ inline float bf2f(ushort h) {
  union { uint u; float f; } v; v.u = ((uint)h) << 16;
  return v.f;
}
__device__ inline void splitbf(float f, ushort& hi, ushort& lo) {
  ushort h = f2bf(f);
  hi = h;
  lo = f2bf(f - bf2f(h));
}

// ---------------------------------------------------------------------------
// prep_w: concatenated transposed weights wt_{hi,lo}[256][128] bf16.
// wt[n][k] = W*[k][n], n in [0,64)=Q, [64,128)=K, [128,256)=V.
// ---------------------------------------------------------------------------
__global__ __launch_bounds__(256) void prep_w(
    const float* __restrict__ wq, const float* __restrict__ wk,
    const float* __restrict__ wv, ushort* __restrict__ wth,
    ushort* __restrict__ wtl) {
  int gid = blockIdx.x * 256 + threadIdx.x;   // 4096 threads
  int n = gid >> 4;
  int k0 = (gid & 15) * 8;
  ushort th[8], tl[8];
#pragma unroll
  for (int j = 0; j < 8; ++j) {
    int k = k0 + j;
    float val = (n < 64)  ? wq[k * W + n]
              : (n < 128) ? wk[k * W + (n - 64)]
                          : wv[k * F + (n - 128)];
    splitbf(val, th[j], tl[j]);
  }
  *(uint4*)&wth[n * 128 + k0] = *(uint4*)th;
  *(uint4*)&wtl[n * 128 + k0] = *(uint4*)tl;
}

// ---------------------------------------------------------------------------
// proj: fused QK+V. One block per 32 x-rows (grid 512, 256 thr = 4 waves).
// x staged ONCE into LDS (coalesced, split hi/lo); waves 0-1 compute Q|K
// features for row-groups 0/1, waves 2-3 compute V features (transposed out).
// Weight fragments come straight from prepped global (L1/L2-resident).
// ---------------------------------------------------------------------------
constexpr int KP = 136;  // 128 + 8 pad (keeps 16B align, only 2-way banks)

__global__ __launch_bounds__(256) void proj_kernel(
    const float* __restrict__ x,
    const ushort* __restrict__ wth, const ushort* __restrict__ wtl,
    ushort* __restrict__ q_h, ushort* __restrict__ q_l,
    ushort* __restrict__ k_h, ushort* __restrict__ k_l,
    ushort* __restrict__ vt_ws) {
  __shared__ ushort xsh[32][KP];   // x hi  (8.7 KB)
  __shared__ ushort xsl[32][KP];   // x lo  (8.7 KB)

  const int tid  = threadIdx.x;
  const int wid  = tid >> 6;             // 0..3
  const int lane = tid & 63;
  const int lg = lane >> 4, li = lane & 15;
  const int pass = wid >> 1;             // 0 = QK, 1 = V
  const int rg   = wid & 1;              // row-group within the 32 rows
  const int brow0 = blockIdx.x * 32;
  const int b    = brow0 / N;
  const int nloc = brow0 % N;

  // stage x tile (32 rows x 128 cols fp32 -> split bf16), fully coalesced
  for (int idx = tid; idx < 32 * 128 / 4; idx += 256) {
    int row = idx >> 5, c4 = idx & 31;
    float4 xv = *(const float4*)&x[(size_t)(brow0 + row) * F + c4 * 4];
    ushort4 h, l;
    splitbf(xv.x, h.x, l.x); splitbf(xv.y, h.y, l.y);
    splitbf(xv.z, h.z, l.z); splitbf(xv.w, h.w, l.w);
    *(ushort4*)&xsh[row][c4 * 4] = h;
    *(ushort4*)&xsl[row][c4 * 4] = l;
  }
  __syncthreads();

  // x fragments for this wave's 16 rows (A/B layouts identical)
  bf16x8 xh[4], xl[4];
#pragma unroll
  for (int kk = 0; kk < 4; ++kk) {
    xh[kk] = *(const bf16x8*)&xsh[rg * 16 + li][kk * 32 + lg * 8];
    xl[kk] = *(const bf16x8*)&xsl[rg * 16 + li][kk * 32 + lg * 8];
  }

  f32x4 zero = {0.f, 0.f, 0.f, 0.f};
  f32x4 acc[8];
#pragma unroll
  for (int t = 0; t < 8; ++t) acc[t] = zero;

  const ushort* wbh = wth + (size_t)pass * 128 * 128;
  const ushort* wbl = wtl + (size_t)pass * 128 * 128;

  if (pass == 0) {
    // D[row][feat] = x . wt^T  (x as A, w as B)
#pragma unroll
    for (int kk = 0; kk < 4; ++kk)
#pragma unroll
      for (int nt = 0; nt < 8; ++nt) {
        bf16x8 bh = *(const bf16x8*)&wbh[(nt * 16 + li) * 128 + kk * 32 + lg * 8];
        bf16x8 bl = *(const bf16x8*)&wbl[(nt * 16 + li) * 128 + kk * 32 + lg * 8];
        acc[nt] = __builtin_amdgcn_mfma_f32_16x16x32_bf16(xh[kk], bh, acc[nt], 0, 0, 0);
        acc[nt] = __builtin_amdgcn_mfma_f32_16x16x32_bf16(xh[kk], bl, acc[nt], 0, 0, 0);
        acc[nt] = __builtin_amdgcn_mfma_f32_16x16x32_bf16(xl[kk], bh, acc[nt], 0, 0, 0);
      }
#pragma unroll
    for (int nt = 0; nt < 8; ++nt)
#pragma unroll
      for (int r = 0; r < 4; ++r) {
        int row = brow0 + rg * 16 + lg * 4 + r;
        int c = nt * 16 + li;
        ushort hv, lv;
        splitbf(acc[nt][r], hv, lv);
        if (nt < 4) { q_h[row * W + c] = hv;        q_l[row * W + c] = lv; }
        else        { k_h[row * W + (c - 64)] = hv; k_l[row * W + (c - 64)] = lv; }
      }
  } else {
    // D[feat][row] = (w as A) . (x as B)  -> coalesced transposed V
#pragma unroll
    for (int kk = 0; kk < 4; ++kk)
#pragma unroll
      for (int mt = 0; mt < 8; ++mt) {
        bf16x8 ah = *(const bf16x8*)&wbh[(mt * 16 + li) * 128 + kk * 32 + lg * 8];
        bf16x8 al = *(const bf16x8*)&wbl[(mt * 16 + li) * 128 + kk * 32 + lg * 8];
        acc[mt] = __builtin_amdgcn_mfma_f32_16x16x32_bf16(ah, xh[kk], acc[mt], 0, 0, 0);
        acc[mt] = __builtin_amdgcn_mfma_f32_16x16x32_bf16(ah, xl[kk], acc[mt], 0, 0, 0);
        acc[mt] = __builtin_amdgcn_mfma_f32_16x16x32_bf16(al, xh[kk], acc[mt], 0, 0, 0);
      }
#pragma unroll
    for (int mt = 0; mt < 8; ++mt)
#pragma unroll
      for (int r = 0; r < 4; ++r) {
        int f = mt * 16 + lg * 4 + r;
        int n = nloc + rg * 16 + li;
        vt_ws[(size_t)b * F * N + (size_t)f * N + n] = f2bf(acc[mt][r]);
      }
  }
}

// ---------------------------------------------------------------------------
// attn: flash attention, K-split, unshifted softmax, S^T orientation.
// Epilogue accumulates unnormalized O directly into `out` via native fp32
// atomics (out pre-zeroed); per-row l accumulates into lsums likewise.
// Grid (N/128, B, KSPLIT), 512 thr.
// ---------------------------------------------------------------------------
constexpr int LP = 72;   // 64 + 8 pad

__global__ __launch_bounds__(512) void attn_kernel(
    const ushort* __restrict__ q_h, const ushort* __restrict__ q_l,
    const ushort* __restrict__ k_h, const ushort* __restrict__ k_l,
    const ushort* __restrict__ vt_ws,
    float* __restrict__ out,      // accumulated unnormalized O
    float* __restrict__ lsums) {  // [B*N] accumulated denominators
  __shared__ ushort ksh[TK][LP];       //  9.2 KB
  __shared__ ushort ksl[TK][LP];       //  9.2 KB
  __shared__ ushort vst[F][LP];        // 18.4 KB  V^T tile [f][key]
  __shared__ ushort ps[8][16][LP];     // 18.4 KB  per-wave P[query][key]

  const int tid  = threadIdx.x;
  const int wid  = tid >> 6;           // 0..7
  const int lane = tid & 63;
  const int lg = lane >> 4, li = lane & 15;
  const int b = blockIdx.y, qt = blockIdx.x, split = blockIdx.z;

  const size_t koffb = (size_t)b * N * W;
  const ushort* vb = vt_ws + (size_t)b * F * N;

  // Q fragments straight from global (this wave's 16 query rows)
  const size_t qrow = (size_t)(b * N + qt * TQ + wid * 16 + li) * W;
  bf16x8 qah[2], qal[2];
  qah[0] = *(const bf16x8*)&q_h[qrow + lg * 8];
  qah[1] = *(const bf16x8*)&q_h[qrow + 32 + lg * 8];
  qal[0] = *(const bf16x8*)&q_l[qrow + lg * 8];
  qal[1] = *(const bf16x8*)&q_l[qrow + 32 + lg * 8];

  float l_lane = 0.f;                  // denominator partial for query row li
  f32x4 zero = {0.f, 0.f, 0.f, 0.f};
  f32x4 o_acc[8];
#pragma unroll
  for (int t = 0; t < 8; ++t) o_acc[t] = zero;

  const int kt0 = split * TILES_PER_SPLIT;
  for (int kt = kt0; kt < kt0 + TILES_PER_SPLIT; ++kt) {
    __syncthreads();
    const size_t koff = koffb + (size_t)kt * TK * W;
    {   // 512 threads: one 16B chunk each for ksh+ksl
      int row = tid >> 3, c8 = tid & 7;
      *(uint4*)&ksh[row][c8 * 8] = *(const uint4*)&k_h[koff + row * W + c8 * 8];
      *(uint4*)&ksl[row][c8 * 8] = *(const uint4*)&k_l[koff + row * W + c8 * 8];
    }
#pragma unroll
    for (int j = 0; j < 2; ++j) {   // 1024 chunks of V^T
      int idx = tid + j * 512, f = idx >> 3, c8 = idx & 7;
      *(uint4*)&vst[f][c8 * 8] = *(const uint4*)&vb[(size_t)f * N + kt * TK + c8 * 8];
    }
    __syncthreads();

    // ---- S^T = K Q^T (split: kh*qh + kh*ql + kl*qh) ----
    f32x4 s_acc[4];
#pragma unroll
    for (int nt = 0; nt < 4; ++nt) s_acc[nt] = zero;
#pragma unroll
    for (int kk = 0; kk < 2; ++kk)
#pragma unroll
      for (int nt = 0; nt < 4; ++nt) {
        bf16x8 kh = *(const bf16x8*)&ksh[nt * 16 + li][kk * 32 + lg * 8];
        bf16x8 kl = *(const bf16x8*)&ksl[nt * 16 + li][kk * 32 + lg * 8];
        s_acc[nt] = __builtin_amdgcn_mfma_f32_16x16x32_bf16(kh, qah[kk], s_acc[nt], 0, 0, 0);
        s_acc[nt] = __builtin_amdgcn_mfma_f32_16x16x32_bf16(kh, qal[kk], s_acc[nt], 0, 0, 0);
        s_acc[nt] = __builtin_amdgcn_mfma_f32_16x16x32_bf16(kl, qah[kk], s_acc[nt], 0, 0, 0);
      }

    // ---- unshifted softmax: lane (lg,li) holds s(query li, key nt*16+lg*4+r) ----
#pragma unroll
    for (int nt = 0; nt < 4; ++nt)
#pragma unroll
      for (int r = 0; r < 4; ++r) {
        float p = __expf(s_acc[nt][r]);
        ushort ph = f2bf(p);
        l_lane += bf2f(ph);   // denominator consistent with bf16 numerator
        ps[wid][li][nt * 16 + lg * 4 + r] = ph;
      }

    // ---- O += P V (wave-private P scratch; same-wave RAW via lgkmcnt) ----
#pragma unroll
    for (int kk = 0; kk < 2; ++kk) {
      bf16x8 pa = *(const bf16x8*)&ps[wid][li][kk * 32 + lg * 8];
#pragma unroll
      for (int ft = 0; ft < 8; ++ft) {
        bf16x8 vf = *(const bf16x8*)&vst[ft * 16 + li][kk * 32 + lg * 8];
        o_acc[ft] = __builtin_amdgcn_mfma_f32_16x16x32_bf16(pa, vf, o_acc[ft], 0, 0, 0);
      }
    }
  }

  // ---- finish l: sum across the 4 lg-lanes sharing query row li ----
  l_lane += __shfl_xor(l_lane, 16, 64);
  l_lane += __shfl_xor(l_lane, 32, 64);

  // ---- epilogue: atomic-accumulate unnormalized partial + l ----
  float* ob = out + (size_t)(b * N + qt * TQ) * F;
#pragma unroll
  for (int r = 0; r < 4; ++r) {
    int row = wid * 16 + lg * 4 + r;
#pragma unroll
    for (int ft = 0; ft < 8; ++ft)
      unsafeAtomicAdd(&ob[row * F + ft * 16 + li], o_acc[ft][r]);
  }
  if (lg == 0)
    unsafeAtomicAdd(&lsums[(size_t)(b * N + qt * TQ) + wid * 16 + li], l_lane);
}

// ---------------------------------------------------------------------------
// normalize: out[row][*] *= 1/l[row]. One float4 per thread.
// ---------------------------------------------------------------------------
__global__ __launch_bounds__(256) void normalize_kernel(
    const float* __restrict__ lsums, float* __restrict__ out) {
  const int gid = blockIdx.x * 256 + threadIdx.x;   // B*N*F/4 threads
  const int row = gid >> 5;            // 32 float4s per row (F=128)
  const int c4  = (gid & 31) * 4;
  const float inv = 1.f / lsums[row];
  float4* p = (float4*)&out[(size_t)row * F + c4];
  float4 v = *p;
  v.x *= inv; v.y *= inv; v.z *= inv; v.w *= inv;
  *p = v;
}

// ---------------------------------------------------------------------------
// Launch
// ---------------------------------------------------------------------------
extern "C" void kernel_launch(void* const* d_in, const int* in_sizes, int n_in,
                              void* d_out, int out_size, void* d_ws, size_t ws_size,
                              hipStream_t stream) {
  // setup_inputs order: x, adj(unused), w_key, w_value, w_query
  const float* x  = (const float*)d_in[0];
  const float* wk = (const float*)d_in[2];
  const float* wv = (const float*)d_in[3];
  const float* wq = (const float*)d_in[4];
  float* out = (float*)d_out;

  constexpr size_t BNW = (size_t)B * N * W;   // 1,048,576
  constexpr size_t BNF = (size_t)B * N * F;   // 2,097,152
  ushort* q_h  = (ushort*)d_ws;
  ushort* q_l  = q_h + BNW;
  ushort* k_h  = q_l + BNW;
  ushort* k_l  = k_h + BNW;
  ushort* vt   = k_l + BNW;                   // BNF u16
  ushort* wth  = vt + BNF;                    // 32768
  ushort* wtl  = wth + 32768;                 // 32768
  float*  ls   = (float*)(wtl + 32768);       // B*N fp32 (64 KB)
  // total ~12.4 MB

  prep_w<<<16, 256, 0, stream>>>(wq, wk, wv, wth, wtl);
  proj_kernel<<<(B * N) / 32, 256, 0, stream>>>(x, wth, wtl,
                                                q_h, q_l, k_h, k_l, vt);
  hipMemsetAsync(out, 0, BNF * sizeof(float), stream);
  hipMemsetAsync(ls, 0, (size_t)B * N * sizeof(float), stream);
  dim3 grid(N / TQ, B, KSPLIT);
  attn_kernel<<<grid, 512, 0, stream>>>(q_h, q_l, k_h, k_l, vt, out, ls);
  normalize_kernel<<<(int)(BNF / 4 / 256), 256, 0, stream>>>(ls, out);
}

// Round 9
// 231.705 us; speedup vs baseline: 1.0916x; 1.0916x over previous
//
#include <hip/hip_runtime.h>
#include <hip/hip_bf16.h>
#include <math.h>

// Problem constants: B=8, N=2048, F=128, W=64
constexpr int B = 8;
constexpr int N = 2048;
constexpr int F = 128;
constexpr int W = 64;

constexpr int TQ = 128;    // query rows per attention block (8 waves)
constexpr int TK = 64;     // key rows per K-tile iteration
constexpr int KSPLIT = 4;  // flash-decoding split over keys
constexpr int TILES_PER_SPLIT = (N / TK) / KSPLIT;   // 8

typedef short bf16x8 __attribute__((ext_vector_type(8)));   // 8 bf16 in 4 VGPRs
typedef float f32x4  __attribute__((ext_vector_type(4)));   // MFMA accumulator

__device__ inline ushort f2bf(float f) {
  union { float f; uint u; } v; v.f = f;
  uint u = v.u;
  return (ushort)((u + 0x7FFFu + ((u >> 16) & 1u)) >> 16);  // RNE
}
__device__ inline float bf2f(ushort h) {
  union { uint u; float f; } v; v.u = ((uint)h) << 16;
  return v.f;
}
__device__ inline void splitbf(float f, ushort& hi, ushort& lo) {
  ushort h = f2bf(f);
  hi = h;
  lo = f2bf(f - bf2f(h));
}

// ---------------------------------------------------------------------------
// prep_w: concatenated transposed weights wt_{hi,lo}[256][128] bf16.
// wt[n][k] = W*[k][n], n in [0,64)=Q, [64,128)=K, [128,256)=V.
// ---------------------------------------------------------------------------
__global__ __launch_bounds__(256) void prep_w(
    const float* __restrict__ wq, const float* __restrict__ wk,
    const float* __restrict__ wv, ushort* __restrict__ wth,
    ushort* __restrict__ wtl) {
  int gid = blockIdx.x * 256 + threadIdx.x;   // 4096 threads
  int n = gid >> 4;
  int k0 = (gid & 15) * 8;
  ushort th[8], tl[8];
#pragma unroll
  for (int j = 0; j < 8; ++j) {
    int k = k0 + j;
    float val = (n < 64)  ? wq[k * W + n]
              : (n < 128) ? wk[k * W + (n - 64)]
                          : wv[k * F + (n - 128)];
    splitbf(val, th[j], tl[j]);
  }
  *(uint4*)&wth[n * 128 + k0] = *(uint4*)th;
  *(uint4*)&wtl[n * 128 + k0] = *(uint4*)tl;
}

// ---------------------------------------------------------------------------
// proj: fused QK+V. One block per 32 x-rows (grid 512, 256 thr = 4 waves).
// x staged ONCE into LDS (coalesced, split hi/lo); waves 0-1 compute Q|K
// features for row-groups 0/1, waves 2-3 compute V features (transposed out).
// Weight fragments come straight from prepped global (L1/L2-resident).
// ---------------------------------------------------------------------------
constexpr int KP = 136;  // 128 + 8 pad (keeps 16B align, only 2-way banks)

__global__ __launch_bounds__(256) void proj_kernel(
    const float* __restrict__ x,
    const ushort* __restrict__ wth, const ushort* __restrict__ wtl,
    ushort* __restrict__ q_h, ushort* __restrict__ q_l,
    ushort* __restrict__ k_h, ushort* __restrict__ k_l,
    ushort* __restrict__ vt_ws) {
  __shared__ ushort xsh[32][KP];   // x hi  (8.7 KB)
  __shared__ ushort xsl[32][KP];   // x lo  (8.7 KB)

  const int tid  = threadIdx.x;
  const int wid  = tid >> 6;             // 0..3
  const int lane = tid & 63;
  const int lg = lane >> 4, li = lane & 15;
  const int pass = wid >> 1;             // 0 = QK, 1 = V
  const int rg   = wid & 1;              // row-group within the 32 rows
  const int brow0 = blockIdx.x * 32;
  const int b    = brow0 / N;
  const int nloc = brow0 % N;

  // stage x tile (32 rows x 128 cols fp32 -> split bf16), fully coalesced
  for (int idx = tid; idx < 32 * 128 / 4; idx += 256) {
    int row = idx >> 5, c4 = idx & 31;
    float4 xv = *(const float4*)&x[(size_t)(brow0 + row) * F + c4 * 4];
    ushort4 h, l;
    splitbf(xv.x, h.x, l.x); splitbf(xv.y, h.y, l.y);
    splitbf(xv.z, h.z, l.z); splitbf(xv.w, h.w, l.w);
    *(ushort4*)&xsh[row][c4 * 4] = h;
    *(ushort4*)&xsl[row][c4 * 4] = l;
  }
  __syncthreads();

  // x fragments for this wave's 16 rows (A/B layouts identical)
  bf16x8 xh[4], xl[4];
#pragma unroll
  for (int kk = 0; kk < 4; ++kk) {
    xh[kk] = *(const bf16x8*)&xsh[rg * 16 + li][kk * 32 + lg * 8];
    xl[kk] = *(const bf16x8*)&xsl[rg * 16 + li][kk * 32 + lg * 8];
  }

  f32x4 zero = {0.f, 0.f, 0.f, 0.f};
  f32x4 acc[8];
#pragma unroll
  for (int t = 0; t < 8; ++t) acc[t] = zero;

  const ushort* wbh = wth + (size_t)pass * 128 * 128;
  const ushort* wbl = wtl + (size_t)pass * 128 * 128;

  if (pass == 0) {
    // D[row][feat] = x . wt^T  (x as A, w as B)
#pragma unroll
    for (int kk = 0; kk < 4; ++kk)
#pragma unroll
      for (int nt = 0; nt < 8; ++nt) {
        bf16x8 bh = *(const bf16x8*)&wbh[(nt * 16 + li) * 128 + kk * 32 + lg * 8];
        bf16x8 bl = *(const bf16x8*)&wbl[(nt * 16 + li) * 128 + kk * 32 + lg * 8];
        acc[nt] = __builtin_amdgcn_mfma_f32_16x16x32_bf16(xh[kk], bh, acc[nt], 0, 0, 0);
        acc[nt] = __builtin_amdgcn_mfma_f32_16x16x32_bf16(xh[kk], bl, acc[nt], 0, 0, 0);
        acc[nt] = __builtin_amdgcn_mfma_f32_16x16x32_bf16(xl[kk], bh, acc[nt], 0, 0, 0);
      }
#pragma unroll
    for (int nt = 0; nt < 8; ++nt)
#pragma unroll
      for (int r = 0; r < 4; ++r) {
        int row = brow0 + rg * 16 + lg * 4 + r;
        int c = nt * 16 + li;
        ushort hv, lv;
        splitbf(acc[nt][r], hv, lv);
        if (nt < 4) { q_h[row * W + c] = hv;        q_l[row * W + c] = lv; }
        else        { k_h[row * W + (c - 64)] = hv; k_l[row * W + (c - 64)] = lv; }
      }
  } else {
    // D[feat][row] = (w as A) . (x as B)  -> coalesced transposed V
#pragma unroll
    for (int kk = 0; kk < 4; ++kk)
#pragma unroll
      for (int mt = 0; mt < 8; ++mt) {
        bf16x8 ah = *(const bf16x8*)&wbh[(mt * 16 + li) * 128 + kk * 32 + lg * 8];
        bf16x8 al = *(const bf16x8*)&wbl[(mt * 16 + li) * 128 + kk * 32 + lg * 8];
        acc[mt] = __builtin_amdgcn_mfma_f32_16x16x32_bf16(ah, xh[kk], acc[mt], 0, 0, 0);
        acc[mt] = __builtin_amdgcn_mfma_f32_16x16x32_bf16(ah, xl[kk], acc[mt], 0, 0, 0);
        acc[mt] = __builtin_amdgcn_mfma_f32_16x16x32_bf16(al, xh[kk], acc[mt], 0, 0, 0);
      }
#pragma unroll
    for (int mt = 0; mt < 8; ++mt)
#pragma unroll
      for (int r = 0; r < 4; ++r) {
        int f = mt * 16 + lg * 4 + r;
        int n = nloc + rg * 16 + li;
        vt_ws[(size_t)b * F * N + (size_t)f * N + n] = f2bf(acc[mt][r]);
      }
  }
}

// ---------------------------------------------------------------------------
// attn: flash attention, K-split, unshifted softmax, S^T orientation.
// Grid (N/128, B, KSPLIT), 512 thr; split s does K-tiles [s*8, s*8+8);
// writes unnormalized O partial + per-row l to its own buffer (op[0]=out).
// NOTE: no atomics — R8 showed cross-XCD same-line atomic accumulation costs
// ~+25 µs vs streaming partial-merge.
// ---------------------------------------------------------------------------
constexpr int LP = 72;   // 64 + 8 pad

__global__ __launch_bounds__(512) void attn_kernel(
    const ushort* __restrict__ q_h, const ushort* __restrict__ q_l,
    const ushort* __restrict__ k_h, const ushort* __restrict__ k_l,
    const ushort* __restrict__ vt_ws,
    float* __restrict__ out,      // split-0 partial
    float* __restrict__ op1,      // split-1 partial
    float* __restrict__ op2,      // split-2 partial
    float* __restrict__ op3,      // split-3 partial
    float* __restrict__ lsums) {  // [KSPLIT][B*N]
  __shared__ ushort ksh[TK][LP];       //  9.2 KB
  __shared__ ushort ksl[TK][LP];       //  9.2 KB
  __shared__ ushort vst[F][LP];        // 18.4 KB  V^T tile [f][key]
  __shared__ ushort ps[8][16][LP];     // 18.4 KB  per-wave P[query][key]

  const int tid  = threadIdx.x;
  const int wid  = tid >> 6;           // 0..7
  const int lane = tid & 63;
  const int lg = lane >> 4, li = lane & 15;
  const int b = blockIdx.y, qt = blockIdx.x, split = blockIdx.z;

  const size_t koffb = (size_t)b * N * W;
  const ushort* vb = vt_ws + (size_t)b * F * N;

  // Q fragments straight from global (this wave's 16 query rows)
  const size_t qrow = (size_t)(b * N + qt * TQ + wid * 16 + li) * W;
  bf16x8 qah[2], qal[2];
  qah[0] = *(const bf16x8*)&q_h[qrow + lg * 8];
  qah[1] = *(const bf16x8*)&q_h[qrow + 32 + lg * 8];
  qal[0] = *(const bf16x8*)&q_l[qrow + lg * 8];
  qal[1] = *(const bf16x8*)&q_l[qrow + 32 + lg * 8];

  float l_lane = 0.f;                  // denominator partial for query row li
  f32x4 zero = {0.f, 0.f, 0.f, 0.f};
  f32x4 o_acc[8];
#pragma unroll
  for (int t = 0; t < 8; ++t) o_acc[t] = zero;

  const int kt0 = split * TILES_PER_SPLIT;
  for (int kt = kt0; kt < kt0 + TILES_PER_SPLIT; ++kt) {
    __syncthreads();
    const size_t koff = koffb + (size_t)kt * TK * W;
    {   // 512 threads: one 16B chunk each for ksh+ksl
      int row = tid >> 3, c8 = tid & 7;
      *(uint4*)&ksh[row][c8 * 8] = *(const uint4*)&k_h[koff + row * W + c8 * 8];
      *(uint4*)&ksl[row][c8 * 8] = *(const uint4*)&k_l[koff + row * W + c8 * 8];
    }
#pragma unroll
    for (int j = 0; j < 2; ++j) {   // 1024 chunks of V^T
      int idx = tid + j * 512, f = idx >> 3, c8 = idx & 7;
      *(uint4*)&vst[f][c8 * 8] = *(const uint4*)&vb[(size_t)f * N + kt * TK + c8 * 8];
    }
    __syncthreads();

    // ---- S^T = K Q^T (split: kh*qh + kh*ql + kl*qh) ----
    f32x4 s_acc[4];
#pragma unroll
    for (int nt = 0; nt < 4; ++nt) s_acc[nt] = zero;
#pragma unroll
    for (int kk = 0; kk < 2; ++kk)
#pragma unroll
      for (int nt = 0; nt < 4; ++nt) {
        bf16x8 kh = *(const bf16x8*)&ksh[nt * 16 + li][kk * 32 + lg * 8];
        bf16x8 kl = *(const bf16x8*)&ksl[nt * 16 + li][kk * 32 + lg * 8];
        s_acc[nt] = __builtin_amdgcn_mfma_f32_16x16x32_bf16(kh, qah[kk], s_acc[nt], 0, 0, 0);
        s_acc[nt] = __builtin_amdgcn_mfma_f32_16x16x32_bf16(kh, qal[kk], s_acc[nt], 0, 0, 0);
        s_acc[nt] = __builtin_amdgcn_mfma_f32_16x16x32_bf16(kl, qah[kk], s_acc[nt], 0, 0, 0);
      }

    // ---- unshifted softmax: lane (lg,li) holds s(query li, key nt*16+lg*4+r) ----
#pragma unroll
    for (int nt = 0; nt < 4; ++nt)
#pragma unroll
      for (int r = 0; r < 4; ++r) {
        float p = __expf(s_acc[nt][r]);
        ushort ph = f2bf(p);
        l_lane += bf2f(ph);   // denominator consistent with bf16 numerator
        ps[wid][li][nt * 16 + lg * 4 + r] = ph;
      }

    // ---- O += P V (wave-private P scratch; same-wave RAW via lgkmcnt) ----
#pragma unroll
    for (int kk = 0; kk < 2; ++kk) {
      bf16x8 pa = *(const bf16x8*)&ps[wid][li][kk * 32 + lg * 8];
#pragma unroll
      for (int ft = 0; ft < 8; ++ft) {
        bf16x8 vf = *(const bf16x8*)&vst[ft * 16 + li][kk * 32 + lg * 8];
        o_acc[ft] = __builtin_amdgcn_mfma_f32_16x16x32_bf16(pa, vf, o_acc[ft], 0, 0, 0);
      }
    }
  }

  // ---- finish l: sum across the 4 lg-lanes sharing query row li ----
  l_lane += __shfl_xor(l_lane, 16, 64);
  l_lane += __shfl_xor(l_lane, 32, 64);

  // ---- epilogue: store UNNORMALIZED partial + l per row ----
  float* opb = (split == 0) ? out : (split == 1) ? op1 : (split == 2) ? op2 : op3;
  float* ob = opb + (size_t)(b * N + qt * TQ) * F;
#pragma unroll
  for (int r = 0; r < 4; ++r) {
    int row = wid * 16 + lg * 4 + r;
#pragma unroll
    for (int ft = 0; ft < 8; ++ft)
      ob[row * F + ft * 16 + li] = o_acc[ft][r];
  }
  if (lg == 0) {
    size_t gr = (size_t)split * B * N + (size_t)(b * N + qt * TQ) + wid * 16 + li;
    lsums[gr] = l_lane;
  }
}

// ---------------------------------------------------------------------------
// combine: merge the four K-split partials. 2 rows per 256-thread block.
// ---------------------------------------------------------------------------
__global__ __launch_bounds__(256) void combine_kernel(
    const float* __restrict__ op1, const float* __restrict__ op2,
    const float* __restrict__ op3, const float* __restrict__ lsums,
    float* __restrict__ out) {
  const int gr  = blockIdx.x * 2 + (threadIdx.x >> 7);
  const int col = threadIdx.x & 127;
  constexpr size_t BN = (size_t)B * N;
  const float l = lsums[gr] + lsums[BN + gr] + lsums[2 * BN + gr] + lsums[3 * BN + gr];
  const float inv = 1.f / l;
  const size_t idx = (size_t)gr * F + col;
  out[idx] = (out[idx] + op1[idx] + op2[idx] + op3[idx]) * inv;
}

// ---------------------------------------------------------------------------
// Launch
// ---------------------------------------------------------------------------
extern "C" void kernel_launch(void* const* d_in, const int* in_sizes, int n_in,
                              void* d_out, int out_size, void* d_ws, size_t ws_size,
                              hipStream_t stream) {
  // setup_inputs order: x, adj(unused), w_key, w_value, w_query
  const float* x  = (const float*)d_in[0];
  const float* wk = (const float*)d_in[2];
  const float* wv = (const float*)d_in[3];
  const float* wq = (const float*)d_in[4];
  float* out = (float*)d_out;

  constexpr size_t BNW = (size_t)B * N * W;   // 1,048,576
  constexpr size_t BNF = (size_t)B * N * F;   // 2,097,152
  ushort* q_h  = (ushort*)d_ws;
  ushort* q_l  = q_h + BNW;
  ushort* k_h  = q_l + BNW;
  ushort* k_l  = k_h + BNW;
  ushort* vt   = k_l + BNW;                   // BNF u16
  ushort* wth  = vt + BNF;                    // 32768
  ushort* wtl  = wth + 32768;                 // 32768
  float*  op1  = (float*)(wtl + 32768);       // BNF fp32
  float*  op2  = op1 + BNF;
  float*  op3  = op2 + BNF;
  float*  ls   = op3 + BNF;                   // KSPLIT*B*N fp32
  // total ~37 MB

  prep_w<<<16, 256, 0, stream>>>(wq, wk, wv, wth, wtl);
  proj_kernel<<<(B * N) / 32, 256, 0, stream>>>(x, wth, wtl,
                                                q_h, q_l, k_h, k_l, vt);
  dim3 grid(N / TQ, B, KSPLIT);
  attn_kernel<<<grid, 512, 0, stream>>>(q_h, q_l, k_h, k_l, vt,
                                        out, op1, op2, op3, ls);
  combine_kernel<<<B * N / 2, 256, 0, stream>>>(op1, op2, op3, ls, out);
}

// Round 10
// 214.148 us; speedup vs baseline: 1.1811x; 1.0820x over previous
//
#include <hip/hip_runtime.h>
#include <hip/hip_bf16.h>
#include <math.h>

// Problem constants: B=8, N=2048, F=128, W=64
constexpr int B = 8;
constexpr int N = 2048;
constexpr int F = 128;
constexpr int W = 64;

constexpr int TQ = 128;    // query rows per attention block (8 waves)
constexpr int TK = 64;     // key rows per K-tile iteration
constexpr int KSPLIT = 4;  // flash-decoding split over keys
constexpr int TILES_PER_SPLIT = (N / TK) / KSPLIT;   // 8

typedef short     bf16x8 __attribute__((ext_vector_type(8)));  // 8 bf16
typedef _Float16  f16x8  __attribute__((ext_vector_type(8)));  // 8 fp16
typedef float     f32x4  __attribute__((ext_vector_type(4)));  // MFMA acc

__device__ inline ushort f2bf(float f) {
  union { float f; uint u; } v; v.f = f;
  uint u = v.u;
  return (ushort)((u + 0x7FFFu + ((u >> 16) & 1u)) >> 16);  // RNE
}
__device__ inline float bf2f(ushort h) {
  union { uint u; float f; } v; v.u = ((uint)h) << 16;
  return v.f;
}

// ---------------------------------------------------------------------------
// prep_w: concatenated transposed weights wt[256][128] fp16.
// wt[n][k] = W*[k][n], n in [0,64)=Q, [64,128)=K, [128,256)=V.
// fp16 (10-bit mantissa) replaces the split-bf16 hi/lo pair: one MFMA per
// product instead of three, with delta-S ~0.02 (<< 0.116 threshold budget).
// ---------------------------------------------------------------------------
__global__ __launch_bounds__(256) void prep_w(
    const float* __restrict__ wq, const float* __restrict__ wk,
    const float* __restrict__ wv, _Float16* __restrict__ wt) {
  int gid = blockIdx.x * 256 + threadIdx.x;   // 4096 threads
  int n = gid >> 4;
  int k0 = (gid & 15) * 8;
  _Float16 t[8];
#pragma unroll
  for (int j = 0; j < 8; ++j) {
    int k = k0 + j;
    float val = (n < 64)  ? wq[k * W + n]
              : (n < 128) ? wk[k * W + (n - 64)]
                          : wv[k * F + (n - 128)];
    t[j] = (_Float16)val;
  }
  *(uint4*)&wt[n * 128 + k0] = *(uint4*)t;
}

// ---------------------------------------------------------------------------
// proj: fused QK+V, fp16 MFMA. One block per 32 x-rows (grid 512, 4 waves).
// x staged ONCE into LDS as fp16; waves 0-1 compute Q|K features (fp16 out),
// waves 2-3 compute V features (transposed, bf16 out — PV path stays bf16).
// ---------------------------------------------------------------------------
constexpr int KP = 136;  // 128 + 8 pad (16B align kept, 2-way banks only)

__global__ __launch_bounds__(256) void proj_kernel(
    const float* __restrict__ x, const _Float16* __restrict__ wt,
    _Float16* __restrict__ q16, _Float16* __restrict__ k16,
    ushort* __restrict__ vt_ws) {
  __shared__ _Float16 xs[32][KP];   // 8.7 KB

  const int tid  = threadIdx.x;
  const int wid  = tid >> 6;             // 0..3
  const int lane = tid & 63;
  const int lg = lane >> 4, li = lane & 15;
  const int pass = wid >> 1;             // 0 = QK, 1 = V
  const int rg   = wid & 1;              // row-group within the 32 rows
  const int brow0 = blockIdx.x * 32;
  const int b    = brow0 / N;
  const int nloc = brow0 % N;

  // stage x tile (32 x 128 fp32 -> fp16), fully coalesced
  for (int idx = tid; idx < 32 * 128 / 4; idx += 256) {
    int row = idx >> 5, c4 = idx & 31;
    float4 xv = *(const float4*)&x[(size_t)(brow0 + row) * F + c4 * 4];
    _Float16 h[4] = {(_Float16)xv.x, (_Float16)xv.y,
                     (_Float16)xv.z, (_Float16)xv.w};
    *(float2*)&xs[row][c4 * 4] = *(float2*)h;
  }
  __syncthreads();

  // x fragments for this wave's 16 rows (A/B layouts identical)
  f16x8 xa[4];
#pragma unroll
  for (int kk = 0; kk < 4; ++kk)
    xa[kk] = *(const f16x8*)&xs[rg * 16 + li][kk * 32 + lg * 8];

  f32x4 zero = {0.f, 0.f, 0.f, 0.f};
  f32x4 acc[8];
#pragma unroll
  for (int t = 0; t < 8; ++t) acc[t] = zero;

  const _Float16* wb = wt + (size_t)pass * 128 * 128;

  if (pass == 0) {
    // D[row][feat] = x . wt^T  (x as A, w as B)
#pragma unroll
    for (int kk = 0; kk < 4; ++kk)
#pragma unroll
      for (int nt = 0; nt < 8; ++nt) {
        f16x8 bw = *(const f16x8*)&wb[(nt * 16 + li) * 128 + kk * 32 + lg * 8];
        acc[nt] = __builtin_amdgcn_mfma_f32_16x16x32_f16(xa[kk], bw, acc[nt], 0, 0, 0);
      }
#pragma unroll
    for (int nt = 0; nt < 8; ++nt)
#pragma unroll
      for (int r = 0; r < 4; ++r) {
        int row = brow0 + rg * 16 + lg * 4 + r;
        int c = nt * 16 + li;
        _Float16 hv = (_Float16)acc[nt][r];
        if (nt < 4) q16[row * W + c] = hv;
        else        k16[row * W + (c - 64)] = hv;
      }
  } else {
    // D[feat][row] = (w as A) . (x as B)  -> coalesced transposed V (bf16)
#pragma unroll
    for (int kk = 0; kk < 4; ++kk)
#pragma unroll
      for (int mt = 0; mt < 8; ++mt) {
        f16x8 aw = *(const f16x8*)&wb[(mt * 16 + li) * 128 + kk * 32 + lg * 8];
        acc[mt] = __builtin_amdgcn_mfma_f32_16x16x32_f16(aw, xa[kk], acc[mt], 0, 0, 0);
      }
#pragma unroll
    for (int mt = 0; mt < 8; ++mt)
#pragma unroll
      for (int r = 0; r < 4; ++r) {
        int f = mt * 16 + lg * 4 + r;
        int n = nloc + rg * 16 + li;
        vt_ws[(size_t)b * F * N + (size_t)f * N + n] = f2bf(acc[mt][r]);
      }
  }
}

// ---------------------------------------------------------------------------
// attn: flash attention, K-split, unshifted softmax, S^T orientation.
// Q/K fp16 (1 MFMA per product); P bf16 (p=e^S can reach e^45 >> fp16 max,
// bf16 has fp32 range); V bf16. LDS 46 KB -> up to 3 blocks/CU.
// Grid (N/128, B, KSPLIT), 512 thr; partials to op[s] (op[0]=out).
// No atomics: R8 showed cross-XCD same-line atomic accumulation costs +25us.
// ---------------------------------------------------------------------------
constexpr int LP = 72;   // 64 + 8 pad

__global__ __launch_bounds__(512) void attn_kernel(
    const _Float16* __restrict__ q16, const _Float16* __restrict__ k16,
    const ushort* __restrict__ vt_ws,
    float* __restrict__ out,      // split-0 partial
    float* __restrict__ op1,      // split-1 partial
    float* __restrict__ op2,      // split-2 partial
    float* __restrict__ op3,      // split-3 partial
    float* __restrict__ lsums) {  // [KSPLIT][B*N]
  __shared__ _Float16 ksh[TK][LP];     //  9.2 KB  K tile fp16
  __shared__ ushort  vst[F][LP];       // 18.4 KB  V^T tile [f][key] bf16
  __shared__ ushort  ps[8][16][LP];    // 18.4 KB  per-wave P[query][key] bf16

  const int tid  = threadIdx.x;
  const int wid  = tid >> 6;           // 0..7
  const int lane = tid & 63;
  const int lg = lane >> 4, li = lane & 15;
  const int b = blockIdx.y, qt = blockIdx.x, split = blockIdx.z;

  const size_t koffb = (size_t)b * N * W;
  const ushort* vb = vt_ws + (size_t)b * F * N;

  // Q fragments straight from global (this wave's 16 query rows)
  const size_t qrow = (size_t)(b * N + qt * TQ + wid * 16 + li) * W;
  f16x8 qa[2];
  qa[0] = *(const f16x8*)&q16[qrow + lg * 8];
  qa[1] = *(const f16x8*)&q16[qrow + 32 + lg * 8];

  float l_lane = 0.f;                  // denominator partial for query row li
  f32x4 zero = {0.f, 0.f, 0.f, 0.f};
  f32x4 o_acc[8];
#pragma unroll
  for (int t = 0; t < 8; ++t) o_acc[t] = zero;

  const int kt0 = split * TILES_PER_SPLIT;
  for (int kt = kt0; kt < kt0 + TILES_PER_SPLIT; ++kt) {
    __syncthreads();
    {   // K tile: 64x64 fp16 = 512 16B-chunks; one per thread
      int row = tid >> 3, c8 = tid & 7;
      *(uint4*)&ksh[row][c8 * 8] =
          *(const uint4*)&k16[koffb + (size_t)kt * TK * W + row * W + c8 * 8];
    }
#pragma unroll
    for (int j = 0; j < 2; ++j) {   // V^T tile: 1024 chunks
      int idx = tid + j * 512, f = idx >> 3, c8 = idx & 7;
      *(uint4*)&vst[f][c8 * 8] = *(const uint4*)&vb[(size_t)f * N + kt * TK + c8 * 8];
    }
    __syncthreads();

    // ---- S^T = K Q^T (single fp16 MFMA per product) ----
    f32x4 s_acc[4];
#pragma unroll
    for (int nt = 0; nt < 4; ++nt) s_acc[nt] = zero;
#pragma unroll
    for (int kk = 0; kk < 2; ++kk)
#pragma unroll
      for (int nt = 0; nt < 4; ++nt) {
        f16x8 kf = *(const f16x8*)&ksh[nt * 16 + li][kk * 32 + lg * 8];
        s_acc[nt] = __builtin_amdgcn_mfma_f32_16x16x32_f16(kf, qa[kk], s_acc[nt], 0, 0, 0);
      }

    // ---- unshifted softmax: lane (lg,li) holds s(query li, key nt*16+lg*4+r).
    // Pack 4 contiguous bf16 p's -> one 8B LDS store (4 stores/tile, not 16).
#pragma unroll
    for (int nt = 0; nt < 4; ++nt) {
      ushort ph[4];
#pragma unroll
      for (int r = 0; r < 4; ++r) {
        float p = __expf(s_acc[nt][r]);
        ph[r] = f2bf(p);
        l_lane += bf2f(ph[r]);   // denominator consistent with bf16 numerator
      }
      *(float2*)&ps[wid][li][nt * 16 + lg * 4] = *(float2*)ph;
    }

    // ---- O += P V (wave-private P scratch; same-wave RAW via lgkmcnt) ----
#pragma unroll
    for (int kk = 0; kk < 2; ++kk) {
      bf16x8 pa = *(const bf16x8*)&ps[wid][li][kk * 32 + lg * 8];
#pragma unroll
      for (int ft = 0; ft < 8; ++ft) {
        bf16x8 vf = *(const bf16x8*)&vst[ft * 16 + li][kk * 32 + lg * 8];
        o_acc[ft] = __builtin_amdgcn_mfma_f32_16x16x32_bf16(pa, vf, o_acc[ft], 0, 0, 0);
      }
    }
  }

  // ---- finish l: sum across the 4 lg-lanes sharing query row li ----
  l_lane += __shfl_xor(l_lane, 16, 64);
  l_lane += __shfl_xor(l_lane, 32, 64);

  // ---- epilogue: store UNNORMALIZED partial + l per row ----
  float* opb = (split == 0) ? out : (split == 1) ? op1 : (split == 2) ? op2 : op3;
  float* ob = opb + (size_t)(b * N + qt * TQ) * F;
#pragma unroll
  for (int r = 0; r < 4; ++r) {
    int row = wid * 16 + lg * 4 + r;
#pragma unroll
    for (int ft = 0; ft < 8; ++ft)
      ob[row * F + ft * 16 + li] = o_acc[ft][r];
  }
  if (lg == 0) {
    size_t gr = (size_t)split * B * N + (size_t)(b * N + qt * TQ) + wid * 16 + li;
    lsums[gr] = l_lane;
  }
}

// ---------------------------------------------------------------------------
// combine: merge the four K-split partials. 2 rows per 256-thread block.
// ---------------------------------------------------------------------------
__global__ __launch_bounds__(256) void combine_kernel(
    const float* __restrict__ op1, const float* __restrict__ op2,
    const float* __restrict__ op3, const float* __restrict__ lsums,
    float* __restrict__ out) {
  const int gr  = blockIdx.x * 2 + (threadIdx.x >> 7);
  const int col = threadIdx.x & 127;
  constexpr size_t BN = (size_t)B * N;
  const float l = lsums[gr] + lsums[BN + gr] + lsums[2 * BN + gr] + lsums[3 * BN + gr];
  const float inv = 1.f / l;
  const size_t idx = (size_t)gr * F + col;
  out[idx] = (out[idx] + op1[idx] + op2[idx] + op3[idx]) * inv;
}

// ---------------------------------------------------------------------------
// Launch
// ---------------------------------------------------------------------------
extern "C" void kernel_launch(void* const* d_in, const int* in_sizes, int n_in,
                              void* d_out, int out_size, void* d_ws, size_t ws_size,
                              hipStream_t stream) {
  // setup_inputs order: x, adj(unused), w_key, w_value, w_query
  const float* x  = (const float*)d_in[0];
  const float* wk = (const float*)d_in[2];
  const float* wv = (const float*)d_in[3];
  const float* wq = (const float*)d_in[4];
  float* out = (float*)d_out;

  constexpr size_t BNW = (size_t)B * N * W;   // 1,048,576
  constexpr size_t BNF = (size_t)B * N * F;   // 2,097,152
  _Float16* q16 = (_Float16*)d_ws;            // BNW fp16
  _Float16* k16 = q16 + BNW;                  // BNW fp16
  ushort*   vt  = (ushort*)(k16 + BNW);       // BNF u16
  _Float16* wt  = (_Float16*)(vt + BNF);      // 256*128 fp16
  float*    op1 = (float*)(wt + 32768);       // BNF fp32
  float*    op2 = op1 + BNF;
  float*    op3 = op2 + BNF;
  float*    ls  = op3 + BNF;                  // KSPLIT*B*N fp32
  // total ~33 MB

  prep_w<<<16, 256, 0, stream>>>(wq, wk, wv, wt);
  proj_kernel<<<(B * N) / 32, 256, 0, stream>>>(x, wt, q16, k16, vt);
  dim3 grid(N / TQ, B, KSPLIT);
  attn_kernel<<<grid, 512, 0, stream>>>(q16, k16, vt, out, op1, op2, op3, ls);
  combine_kernel<<<B * N / 2, 256, 0, stream>>>(op1, op2, op3, ls, out);
}

// Round 11
// 210.527 us; speedup vs baseline: 1.2015x; 1.0172x over previous
//
#include <hip/hip_runtime.h>
#include <hip/hip_bf16.h>
#include <math.h>

// Problem constants: B=8, N=2048, F=128, W=64
constexpr int B = 8;
constexpr int N = 2048;
constexpr int F = 128;
constexpr int W = 64;

constexpr int TQ = 128;    // query rows per attention block (8 waves)
constexpr int TK = 64;     // key rows per K-tile iteration
constexpr int KSPLIT = 4;  // flash-decoding split over keys
constexpr int TILES_PER_SPLIT = (N / TK) / KSPLIT;   // 8

typedef short     bf16x8 __attribute__((ext_vector_type(8)));  // 8 bf16
typedef _Float16  f16x8  __attribute__((ext_vector_type(8)));  // 8 fp16
typedef float     f32x4  __attribute__((ext_vector_type(4)));  // MFMA acc

__device__ inline ushort f2bf(float f) {
  union { float f; uint u; } v; v.f = f;
  uint u = v.u;
  return (ushort)((u + 0x7FFFu + ((u >> 16) & 1u)) >> 16);  // RNE
}
__device__ inline float bf2f(ushort h) {
  union { uint u; float f; } v; v.u = ((uint)h) << 16;
  return v.f;
}

// Barrier that orders LDS only (lgkmcnt), leaving global loads (vmcnt) in
// flight — __syncthreads() would drain vmcnt(0) and kill cross-tile prefetch.
__device__ inline void lgkm_barrier() {
  asm volatile("s_waitcnt lgkmcnt(0)" ::: "memory");
  __builtin_amdgcn_s_barrier();
}

// ---------------------------------------------------------------------------
// prep_w: concatenated transposed weights wt[256][128] fp16.
// wt[n][k] = W*[k][n], n in [0,64)=Q, [64,128)=K, [128,256)=V.
// ---------------------------------------------------------------------------
__global__ __launch_bounds__(256) void prep_w(
    const float* __restrict__ wq, const float* __restrict__ wk,
    const float* __restrict__ wv, _Float16* __restrict__ wt) {
  int gid = blockIdx.x * 256 + threadIdx.x;   // 4096 threads
  int n = gid >> 4;
  int k0 = (gid & 15) * 8;
  _Float16 t[8];
#pragma unroll
  for (int j = 0; j < 8; ++j) {
    int k = k0 + j;
    float val = (n < 64)  ? wq[k * W + n]
              : (n < 128) ? wk[k * W + (n - 64)]
                          : wv[k * F + (n - 128)];
    t[j] = (_Float16)val;
  }
  *(uint4*)&wt[n * 128 + k0] = *(uint4*)t;
}

// ---------------------------------------------------------------------------
// proj: fused QK+V, fp16 MFMA. One block per 32 x-rows (grid 512, 4 waves).
// x staged ONCE into LDS as fp16; waves 0-1 compute Q|K features (fp16 out),
// waves 2-3 compute V features (transposed, bf16 out — PV path stays bf16).
// ---------------------------------------------------------------------------
constexpr int KP = 136;  // 128 + 8 pad (16B align kept, 2-way banks only)

__global__ __launch_bounds__(256) void proj_kernel(
    const float* __restrict__ x, const _Float16* __restrict__ wt,
    _Float16* __restrict__ q16, _Float16* __restrict__ k16,
    ushort* __restrict__ vt_ws) {
  __shared__ _Float16 xs[32][KP];   // 8.7 KB

  const int tid  = threadIdx.x;
  const int wid  = tid >> 6;             // 0..3
  const int lane = tid & 63;
  const int lg = lane >> 4, li = lane & 15;
  const int pass = wid >> 1;             // 0 = QK, 1 = V
  const int rg   = wid & 1;              // row-group within the 32 rows
  const int brow0 = blockIdx.x * 32;
  const int b    = brow0 / N;
  const int nloc = brow0 % N;

  // stage x tile (32 x 128 fp32 -> fp16), fully coalesced
  for (int idx = tid; idx < 32 * 128 / 4; idx += 256) {
    int row = idx >> 5, c4 = idx & 31;
    float4 xv = *(const float4*)&x[(size_t)(brow0 + row) * F + c4 * 4];
    _Float16 h[4] = {(_Float16)xv.x, (_Float16)xv.y,
                     (_Float16)xv.z, (_Float16)xv.w};
    *(float2*)&xs[row][c4 * 4] = *(float2*)h;
  }
  __syncthreads();

  // x fragments for this wave's 16 rows (A/B layouts identical)
  f16x8 xa[4];
#pragma unroll
  for (int kk = 0; kk < 4; ++kk)
    xa[kk] = *(const f16x8*)&xs[rg * 16 + li][kk * 32 + lg * 8];

  f32x4 zero = {0.f, 0.f, 0.f, 0.f};
  f32x4 acc[8];
#pragma unroll
  for (int t = 0; t < 8; ++t) acc[t] = zero;

  const _Float16* wb = wt + (size_t)pass * 128 * 128;

  if (pass == 0) {
    // D[row][feat] = x . wt^T  (x as A, w as B)
#pragma unroll
    for (int kk = 0; kk < 4; ++kk)
#pragma unroll
      for (int nt = 0; nt < 8; ++nt) {
        f16x8 bw = *(const f16x8*)&wb[(nt * 16 + li) * 128 + kk * 32 + lg * 8];
        acc[nt] = __builtin_amdgcn_mfma_f32_16x16x32_f16(xa[kk], bw, acc[nt], 0, 0, 0);
      }
#pragma unroll
    for (int nt = 0; nt < 8; ++nt)
#pragma unroll
      for (int r = 0; r < 4; ++r) {
        int row = brow0 + rg * 16 + lg * 4 + r;
        int c = nt * 16 + li;
        _Float16 hv = (_Float16)acc[nt][r];
        if (nt < 4) q16[row * W + c] = hv;
        else        k16[row * W + (c - 64)] = hv;
      }
  } else {
    // D[feat][row] = (w as A) . (x as B)  -> coalesced transposed V (bf16)
#pragma unroll
    for (int kk = 0; kk < 4; ++kk)
#pragma unroll
      for (int mt = 0; mt < 8; ++mt) {
        f16x8 aw = *(const f16x8*)&wb[(mt * 16 + li) * 128 + kk * 32 + lg * 8];
        acc[mt] = __builtin_amdgcn_mfma_f32_16x16x32_f16(aw, xa[kk], acc[mt], 0, 0, 0);
      }
#pragma unroll
    for (int mt = 0; mt < 8; ++mt)
#pragma unroll
      for (int r = 0; r < 4; ++r) {
        int f = mt * 16 + lg * 4 + r;
        int n = nloc + rg * 16 + li;
        vt_ws[(size_t)b * F * N + (size_t)f * N + n] = f2bf(acc[mt][r]);
      }
  }
}

// ---------------------------------------------------------------------------
// attn: flash attention, K-split, unshifted softmax, S^T orientation.
// Pipelined K-loop: lgkm-only barriers keep next tile's global loads in
// flight across the whole compute phase (vmcnt waited only at next LDS-write).
// Partials stored bf16 (combine traffic halved). Grid (N/128, B, KSPLIT).
// ---------------------------------------------------------------------------
constexpr int LP = 72;   // 64 + 8 pad

__global__ __launch_bounds__(512) void attn_kernel(
    const _Float16* __restrict__ q16, const _Float16* __restrict__ k16,
    const ushort* __restrict__ vt_ws,
    ushort* __restrict__ op0, ushort* __restrict__ op1,
    ushort* __restrict__ op2, ushort* __restrict__ op3,
    float* __restrict__ lsums) {  // [KSPLIT][B*N]
  __shared__ _Float16 ksh[TK][LP];     //  9.2 KB  K tile fp16
  __shared__ ushort  vst[F][LP];       // 18.4 KB  V^T tile [f][key] bf16
  __shared__ ushort  ps[8][16][LP];    // 18.4 KB  per-wave P[query][key] bf16

  const int tid  = threadIdx.x;
  const int wid  = tid >> 6;           // 0..7
  const int lane = tid & 63;
  const int lg = lane >> 4, li = lane & 15;
  const int b = blockIdx.y, qt = blockIdx.x, split = blockIdx.z;

  const size_t koffb = (size_t)b * N * W;
  const ushort* vb = vt_ws + (size_t)b * F * N;

  // Q fragments straight from global (this wave's 16 query rows)
  const size_t qrow = (size_t)(b * N + qt * TQ + wid * 16 + li) * W;
  f16x8 qa[2];
  qa[0] = *(const f16x8*)&q16[qrow + lg * 8];
  qa[1] = *(const f16x8*)&q16[qrow + 32 + lg * 8];

  // staging addresses (fixed per thread)
  const int krow = tid >> 3, kc8 = tid & 7;           // K chunk
  const int vf0 = tid >> 3, vf1 = (tid + 512) >> 3;   // V chunks
  const int vc8 = tid & 7;

  // register prefetch buffers for the next tile
  uint4 kr, vr0, vr1;
  auto load_tile = [&](int kt) {
    kr  = *(const uint4*)&k16[koffb + (size_t)kt * TK * W + krow * W + kc8 * 8];
    vr0 = *(const uint4*)&vb[(size_t)vf0 * N + kt * TK + vc8 * 8];
    vr1 = *(const uint4*)&vb[(size_t)vf1 * N + kt * TK + vc8 * 8];
  };

  float l_lane = 0.f;                  // denominator partial for query row li
  f32x4 zero = {0.f, 0.f, 0.f, 0.f};
  f32x4 o_acc[8];
#pragma unroll
  for (int t = 0; t < 8; ++t) o_acc[t] = zero;

  const int kt0 = split * TILES_PER_SPLIT;
  load_tile(kt0);

  for (int kt = kt0; kt < kt0 + TILES_PER_SPLIT; ++kt) {
    // barrier A: all waves done READING ksh/vst of previous tile (lgkm only)
    lgkm_barrier();
    // drain prefetched regs into LDS (compiler inserts the vmcnt wait here)
    *(uint4*)&ksh[krow][kc8 * 8] = kr;
    *(uint4*)&vst[vf0][vc8 * 8] = vr0;
    *(uint4*)&vst[vf1][vc8 * 8] = vr1;
    // issue next tile's loads NOW — they stay in flight across compute
    if (kt + 1 < kt0 + TILES_PER_SPLIT) load_tile(kt + 1);
    // barrier B: LDS writes visible (lgkm only; vmcnt stays outstanding)
    lgkm_barrier();

    // ---- S^T = K Q^T (single fp16 MFMA per product) ----
    f32x4 s_acc[4];
#pragma unroll
    for (int nt = 0; nt < 4; ++nt) s_acc[nt] = zero;
#pragma unroll
    for (int kk = 0; kk < 2; ++kk)
#pragma unroll
      for (int nt = 0; nt < 4; ++nt) {
        f16x8 kf = *(const f16x8*)&ksh[nt * 16 + li][kk * 32 + lg * 8];
        s_acc[nt] = __builtin_amdgcn_mfma_f32_16x16x32_f16(kf, qa[kk], s_acc[nt], 0, 0, 0);
      }

    // ---- unshifted softmax: lane (lg,li) holds s(query li, key nt*16+lg*4+r).
#pragma unroll
    for (int nt = 0; nt < 4; ++nt) {
      ushort ph[4];
#pragma unroll
      for (int r = 0; r < 4; ++r) {
        float p = __expf(s_acc[nt][r]);
        ph[r] = f2bf(p);
        l_lane += bf2f(ph[r]);   // denominator consistent with bf16 numerator
      }
      *(float2*)&ps[wid][li][nt * 16 + lg * 4] = *(float2*)ph;
    }

    // ---- O += P V (wave-private P scratch; same-wave RAW via lgkmcnt) ----
#pragma unroll
    for (int kk = 0; kk < 2; ++kk) {
      bf16x8 pa = *(const bf16x8*)&ps[wid][li][kk * 32 + lg * 8];
#pragma unroll
      for (int ft = 0; ft < 8; ++ft) {
        bf16x8 vf = *(const bf16x8*)&vst[ft * 16 + li][kk * 32 + lg * 8];
        o_acc[ft] = __builtin_amdgcn_mfma_f32_16x16x32_bf16(pa, vf, o_acc[ft], 0, 0, 0);
      }
    }
  }

  // ---- finish l: sum across the 4 lg-lanes sharing query row li ----
  l_lane += __shfl_xor(l_lane, 16, 64);
  l_lane += __shfl_xor(l_lane, 32, 64);

  // ---- epilogue: store UNNORMALIZED bf16 partial + l per row ----
  ushort* opb = (split == 0) ? op0 : (split == 1) ? op1 : (split == 2) ? op2 : op3;
  ushort* ob = opb + (size_t)(b * N + qt * TQ) * F;
#pragma unroll
  for (int r = 0; r < 4; ++r) {
    int row = wid * 16 + lg * 4 + r;
#pragma unroll
    for (int ft = 0; ft < 8; ++ft)
      ob[row * F + ft * 16 + li] = f2bf(o_acc[ft][r]);
  }
  if (lg == 0) {
    size_t gr = (size_t)split * B * N + (size_t)(b * N + qt * TQ) + wid * 16 + li;
    lsums[gr] = l_lane;
  }
}

// ---------------------------------------------------------------------------
// combine: merge the four bf16 K-split partials. 2 rows per 256-thread block.
// ---------------------------------------------------------------------------
__global__ __launch_bounds__(256) void combine_kernel(
    const ushort* __restrict__ op0, const ushort* __restrict__ op1,
    const ushort* __restrict__ op2, const ushort* __restrict__ op3,
    const float* __restrict__ lsums, float* __restrict__ out) {
  const int gr  = blockIdx.x * 2 + (threadIdx.x >> 7);
  const int col = threadIdx.x & 127;
  constexpr size_t BN = (size_t)B * N;
  const float l = lsums[gr] + lsums[BN + gr] + lsums[2 * BN + gr] + lsums[3 * BN + gr];
  const float inv = 1.f / l;
  const size_t idx = (size_t)gr * F + col;
  out[idx] = (bf2f(op0[idx]) + bf2f(op1[idx]) + bf2f(op2[idx]) + bf2f(op3[idx])) * inv;
}

// ---------------------------------------------------------------------------
// Launch
// ---------------------------------------------------------------------------
extern "C" void kernel_launch(void* const* d_in, const int* in_sizes, int n_in,
                              void* d_out, int out_size, void* d_ws, size_t ws_size,
                              hipStream_t stream) {
  // setup_inputs order: x, adj(unused), w_key, w_value, w_query
  const float* x  = (const float*)d_in[0];
  const float* wk = (const float*)d_in[2];
  const float* wv = (const float*)d_in[3];
  const float* wq = (const float*)d_in[4];
  float* out = (float*)d_out;

  constexpr size_t BNW = (size_t)B * N * W;   // 1,048,576
  constexpr size_t BNF = (size_t)B * N * F;   // 2,097,152
  _Float16* q16 = (_Float16*)d_ws;            // BNW fp16
  _Float16* k16 = q16 + BNW;                  // BNW fp16
  ushort*   vt  = (ushort*)(k16 + BNW);       // BNF u16
  _Float16* wt  = (_Float16*)(vt + BNF);      // 256*128 fp16
  ushort*   op0 = (ushort*)(wt + 32768);      // BNF u16 partials x4
  ushort*   op1 = op0 + BNF;
  ushort*   op2 = op1 + BNF;
  ushort*   op3 = op2 + BNF;
  float*    ls  = (float*)(op3 + BNF);        // KSPLIT*B*N fp32
  // total ~25 MB

  prep_w<<<16, 256, 0, stream>>>(wq, wk, wv, wt);
  proj_kernel<<<(B * N) / 32, 256, 0, stream>>>(x, wt, q16, k16, vt);
  dim3 grid(N / TQ, B, KSPLIT);
  attn_kernel<<<grid, 512, 0, stream>>>(q16, k16, vt, op0, op1, op2, op3, ls);
  combine_kernel<<<B * N / 2, 256, 0, stream>>>(op0, op1, op2, op3, ls, out);
}